// Round 1
// baseline (392.907 us; speedup 1.0000x reference)
//
#include <hip/hip_runtime.h>
#include <cstdint>

#define BB 2
#define SS 2048
#define DD 2048
#define HH 16
#define HDIM 128
#define MM (BB * SS)  // 4096

typedef __attribute__((ext_vector_type(8))) short bf16x8;
typedef __attribute__((ext_vector_type(4))) short bf16x4;
typedef __attribute__((ext_vector_type(4))) float f32x4;

__device__ inline short f2bf(float f) {
  union { float f; unsigned u; } v; v.f = f;
  unsigned r = v.u + 0x7FFFu + ((v.u >> 16) & 1u);
  return (short)(r >> 16);
}
__device__ inline float bf2f(short s) {
  union { float f; unsigned u; } v;
  v.u = ((unsigned)(unsigned short)s) << 16;
  return v.f;
}

__device__ inline void gll16(const void* g, void* l) {
  __builtin_amdgcn_global_load_lds(
      (const __attribute__((address_space(1))) void*)g,
      (__attribute__((address_space(3))) void*)l, 16, 0, 0);
}

// ---------------- cast fp32 -> bf16 ----------------
__global__ __launch_bounds__(256) void cast_bf16_kernel(
    const float* __restrict__ x, short* __restrict__ y, int n4) {
  int i = blockIdx.x * 256 + threadIdx.x;
  if (i >= n4) return;
  float4 v = reinterpret_cast<const float4*>(x)[i];
  bf16x4 o;
  o[0] = f2bf(v.x); o[1] = f2bf(v.y); o[2] = f2bf(v.z); o[3] = f2bf(v.w);
  reinterpret_cast<bf16x4*>(y)[i] = o;
}

// ---------------- transpose+cast weight (K,N)fp32 -> (N,K)bf16 ----------------
__global__ __launch_bounds__(256) void transpose_cast_kernel(
    const float* __restrict__ W, short* __restrict__ Wt) {
  __shared__ short tile[64][65];
  int c = threadIdx.x & 63, r4 = threadIdx.x >> 6;
  int n0 = blockIdx.x << 6, k0 = blockIdx.y << 6;
#pragma unroll
  for (int p = 0; p < 16; ++p) {
    int r = (p << 2) + r4;
    tile[c][r] = f2bf(W[(size_t)(k0 + r) * DD + n0 + c]);
  }
  __syncthreads();
#pragma unroll
  for (int p = 0; p < 16; ++p) {
    int r = (p << 2) + r4;
    Wt[(size_t)(n0 + r) * DD + k0 + c] = tile[r][c];
  }
}

// ---------------- transpose V (B,S,D) bf16 head-slices -> Vt (B*H, 128, S) ----------------
__global__ __launch_bounds__(256) void transpose_v_kernel(
    const short* __restrict__ V, short* __restrict__ Vt) {
  __shared__ short tile[64][65];
  int c = threadIdx.x & 63, r4 = threadIdx.x >> 6;
  int s0 = blockIdx.x << 6, d0 = blockIdx.y << 6;
  int bh = blockIdx.z;
  int b = bh >> 4, h = bh & 15;
#pragma unroll
  for (int p = 0; p < 16; ++p) {
    int r = (p << 2) + r4;  // s-local
    tile[c][r] = V[(size_t)(b * SS + s0 + r) * DD + h * HDIM + d0 + c];
  }
  __syncthreads();
#pragma unroll
  for (int p = 0; p < 16; ++p) {
    int r = (p << 2) + r4;  // d-local
    Vt[((size_t)bh * HDIM + d0 + r) * SS + s0 + c] = tile[r][c];
  }
}

// ---------------- RoPE in-place on Q and K (bf16) ----------------
__global__ __launch_bounds__(256) void rope_kernel(
    short* __restrict__ Q, short* __restrict__ K,
    const float* __restrict__ fc, const float* __restrict__ fs) {
  int idx = blockIdx.x * 256 + threadIdx.x;  // MM * 256 total
  int m = idx >> 8;
  int c8 = idx & 255;            // 8-elem chunk within row
  int s = m & (SS - 1);
  int i0 = (c8 & 15) << 2;       // pair index base within head
  float4 c4 = *reinterpret_cast<const float4*>(&fc[s * 64 + i0]);
  float4 s4 = *reinterpret_cast<const float4*>(&fs[s * 64 + i0]);
  float cc[4] = {c4.x, c4.y, c4.z, c4.w};
  float sn[4] = {s4.x, s4.y, s4.z, s4.w};
  size_t off = (size_t)m * DD + (c8 << 3);
  {
    bf16x8 v = *reinterpret_cast<bf16x8*>(&Q[off]);
    bf16x8 o;
#pragma unroll
    for (int p = 0; p < 4; ++p) {
      float e = bf2f(v[2 * p]), od = bf2f(v[2 * p + 1]);
      o[2 * p] = f2bf(e * cc[p] - od * sn[p]);
      o[2 * p + 1] = f2bf(e * sn[p] + od * cc[p]);
    }
    *reinterpret_cast<bf16x8*>(&Q[off]) = o;
  }
  {
    bf16x8 v = *reinterpret_cast<bf16x8*>(&K[off]);
    bf16x8 o;
#pragma unroll
    for (int p = 0; p < 4; ++p) {
      float e = bf2f(v[2 * p]), od = bf2f(v[2 * p + 1]);
      o[2 * p] = f2bf(e * cc[p] - od * sn[p]);
      o[2 * p + 1] = f2bf(e * sn[p] + od * cc[p]);
    }
    *reinterpret_cast<bf16x8*>(&K[off]) = o;
  }
}

// ---------------- GEMM: C(M,N) = A(M,K) * Bt(N,K)^T, bf16 in, OT out ----------------
// 128x128 tile, BK=64, 4 waves (2x2), each wave 64x64 = 4x4 16x16 frags.
// global_load_lds width 16 with pre-swizzled global source (seg ^= row&7);
// frag reads deswizzle with ^((row&7)<<3) shorts.
template <typename OT>
__global__ __launch_bounds__(256) void gemm_kernel(
    const short* __restrict__ A, const short* __restrict__ Bt, OT* __restrict__ C,
    int Mdim, int Ndim, int Kdim) {
  __shared__ short As[128 * 64];
  __shared__ short Bs[128 * 64];
  int tid = threadIdx.x;
  int lane = tid & 63, w = tid >> 6;
  int cl = lane & 15, gq = lane >> 4;
  int wm = w >> 1, wn = w & 1;
  int m0 = blockIdx.y << 7, n0 = blockIdx.x << 7;
  f32x4 acc[4][4];
#pragma unroll
  for (int i = 0; i < 4; ++i)
#pragma unroll
    for (int j = 0; j < 4; ++j) {
      f32x4 z = {0.f, 0.f, 0.f, 0.f};
      acc[i][j] = z;
    }
  int lrow = lane >> 3;                // 0..7 within 8-row group
  int lseg = (lane & 7) ^ lrow;        // pre-swizzled source segment

  for (int k0 = 0; k0 < Kdim; k0 += 64) {
#pragma unroll
    for (int i = 0; i < 4; ++i) {
      int r0 = ((w << 2) + i) << 3;    // 8-row group base
      gll16(&A[(size_t)(m0 + r0 + lrow) * Kdim + k0 + (lseg << 3)], &As[r0 << 6]);
      gll16(&Bt[(size_t)(n0 + r0 + lrow) * Kdim + k0 + (lseg << 3)], &Bs[r0 << 6]);
    }
    __syncthreads();
#pragma unroll
    for (int ks = 0; ks < 2; ++ks) {
      bf16x8 af[4], bfr[4];
#pragma unroll
      for (int f = 0; f < 4; ++f) {
        int ra = (wm << 6) + (f << 4) + cl;
        af[f] = *reinterpret_cast<const bf16x8*>(
            &As[((ra << 6) + (ks << 5) + (gq << 3)) ^ ((ra & 7) << 3)]);
        int rb = (wn << 6) + (f << 4) + cl;
        bfr[f] = *reinterpret_cast<const bf16x8*>(
            &Bs[((rb << 6) + (ks << 5) + (gq << 3)) ^ ((rb & 7) << 3)]);
      }
#pragma unroll
      for (int fm = 0; fm < 4; ++fm)
#pragma unroll
        for (int fn = 0; fn < 4; ++fn)
          acc[fm][fn] = __builtin_amdgcn_mfma_f32_16x16x32_bf16(
              af[fm], bfr[fn], acc[fm][fn], 0, 0, 0);
    }
    __syncthreads();
  }
  // epilogue: C row = (gq*4 + r), col = cl within each 16x16 frag
#pragma unroll
  for (int fm = 0; fm < 4; ++fm)
#pragma unroll
    for (int r = 0; r < 4; ++r) {
      int mrow = m0 + (wm << 6) + (fm << 4) + (gq << 2) + r;
#pragma unroll
      for (int fn = 0; fn < 4; ++fn) {
        int ncol = n0 + (wn << 6) + (fn << 4) + cl;
        float vv = acc[fm][fn][r];
        if constexpr (sizeof(OT) == 2)
          C[(size_t)mrow * Ndim + ncol] = (OT)f2bf(vv);
        else
          C[(size_t)mrow * Ndim + ncol] = vv;
      }
    }
}

// ---------------- flash attention ----------------
// grid (S/64, B*H); 256 threads = 4 waves; wave w owns Q rows [q0+w*16, +16)
// K (B,S,D) bf16 roped; Vt (B*H,128,S) bf16; out (B,S,D) bf16
__global__ __launch_bounds__(256) void attn_kernel(
    const short* __restrict__ Q, const short* __restrict__ K,
    const short* __restrict__ Vt, short* __restrict__ O) {
  __shared__ short Kl[64 * 128];   // [kvrow][d], XOR-swizzled
  __shared__ short Vl[128 * 64];   // [d][kvrow], XOR-swizzled
  __shared__ short Pl[4 * 16 * 64];  // per-wave P, XOR-swizzled
  const int qt = blockIdx.x;
  const int bh = blockIdx.y;
  const int b = bh >> 4, h = bh & 15;
  const int tid = threadIdx.x;
  const int lane = tid & 63, w = tid >> 6;
  const int cl = lane & 15, gq = lane >> 4;
  const int q0 = qt << 6;
  const float scale = 0.08838834764831845f;  // 1/sqrt(128)

  // Q fragments hoisted (A-operand: row = cl, k = gq*8 (+ks*32))
  bf16x8 qf[4];
  const size_t qrow = ((size_t)b * SS + q0 + w * 16 + cl) * DD + h * HDIM;
#pragma unroll
  for (int ks = 0; ks < 4; ++ks)
    qf[ks] = *reinterpret_cast<const bf16x8*>(&Q[qrow + ks * 32 + gq * 8]);

  f32x4 o[8];
#pragma unroll
  for (int i = 0; i < 8; ++i) { f32x4 z = {0.f, 0.f, 0.f, 0.f}; o[i] = z; }
  float mrow[4] = {-INFINITY, -INFINITY, -INFINITY, -INFINITY};
  float lrow[4] = {0.f, 0.f, 0.f, 0.f};

  for (int t = 0; t <= qt; ++t) {
    // stage K tile [64][128] and V tile [128][64] (transposed layout), swizzled
#pragma unroll
    for (int it = 0; it < 4; ++it) {
      int id = it * 256 + tid;
      int row = id >> 4, seg = id & 15;  // K: 64 rows x 16 segs
      bf16x8 kv = *reinterpret_cast<const bf16x8*>(
          &K[((size_t)b * SS + t * 64 + row) * DD + h * HDIM + seg * 8]);
      *reinterpret_cast<bf16x8*>(&Kl[(row * 128 + seg * 8) ^ ((row & 7) << 3)]) = kv;
      int d = id >> 3, sg = id & 7;      // V: 128 rows x 8 segs
      bf16x8 vv = *reinterpret_cast<const bf16x8*>(
          &Vt[((size_t)bh * HDIM + d) * SS + t * 64 + sg * 8]);
      *reinterpret_cast<bf16x8*>(&Vl[(d * 64 + sg * 8) ^ ((d & 7) << 3)]) = vv;
    }
    __syncthreads();

    // S = Q K^T  (4 col-blocks x 4 k-steps)
    f32x4 sa[4];
#pragma unroll
    for (int nb = 0; nb < 4; ++nb) { f32x4 z = {0.f, 0.f, 0.f, 0.f}; sa[nb] = z; }
#pragma unroll
    for (int nb = 0; nb < 4; ++nb) {
      int rk = nb * 16 + cl;
#pragma unroll
      for (int ks = 0; ks < 4; ++ks) {
        bf16x8 kf = *reinterpret_cast<const bf16x8*>(
            &Kl[((rk * 128) + ks * 32 + gq * 8) ^ ((rk & 7) << 3)]);
        sa[nb] = __builtin_amdgcn_mfma_f32_16x16x32_bf16(qf[ks], kf, sa[nb], 0, 0, 0);
      }
    }
    // scale + causal mask (only the diagonal tile is partial)
#pragma unroll
    for (int nb = 0; nb < 4; ++nb)
#pragma unroll
      for (int r = 0; r < 4; ++r) sa[nb][r] *= scale;
    if (t == qt) {
#pragma unroll
      for (int nb = 0; nb < 4; ++nb) {
        int cg = nb * 16 + cl;
#pragma unroll
        for (int r = 0; r < 4; ++r) {
          int rg = w * 16 + gq * 4 + r;
          if (cg > rg) sa[nb][r] = -1e30f;
        }
      }
    }
    // online softmax (rows live across the 16 cl-lanes of each gq group)
    float al[4];
#pragma unroll
    for (int r = 0; r < 4; ++r) {
      float mr = fmaxf(fmaxf(sa[0][r], sa[1][r]), fmaxf(sa[2][r], sa[3][r]));
#pragma unroll
      for (int off = 1; off < 16; off <<= 1)
        mr = fmaxf(mr, __shfl_xor(mr, off, 64));
      float mn = fmaxf(mrow[r], mr);
      al[r] = __expf(mrow[r] - mn);
      mrow[r] = mn;
      float ps = 0.f;
#pragma unroll
      for (int nb = 0; nb < 4; ++nb) {
        float p = __expf(sa[nb][r] - mn);
        sa[nb][r] = p;
        ps += p;
      }
#pragma unroll
      for (int off = 1; off < 16; off <<= 1) ps += __shfl_xor(ps, off, 64);
      lrow[r] = lrow[r] * al[r] + ps;
    }
#pragma unroll
    for (int dn = 0; dn < 8; ++dn)
#pragma unroll
      for (int r = 0; r < 4; ++r) o[dn][r] *= al[r];

    // write P (bf16) to per-wave LDS region, swizzled
#pragma unroll
    for (int nb = 0; nb < 4; ++nb)
#pragma unroll
      for (int r = 0; r < 4; ++r) {
        int row = gq * 4 + r, col = nb * 16 + cl;
        Pl[w * 1024 + ((row * 64 + col) ^ ((row & 7) << 3))] = f2bf(sa[nb][r]);
      }

    // O += P V  (8 d-blocks x 2 k-steps)
#pragma unroll
    for (int dn = 0; dn < 8; ++dn) {
      int rv = dn * 16 + cl;
#pragma unroll
      for (int ks = 0; ks < 2; ++ks) {
        bf16x8 pf = *reinterpret_cast<const bf16x8*>(
            &Pl[w * 1024 + ((cl * 64 + ks * 32 + gq * 8) ^ ((cl & 7) << 3))]);
        bf16x8 vf = *reinterpret_cast<const bf16x8*>(
            &Vl[(rv * 64 + ks * 32 + gq * 8) ^ ((rv & 7) << 3)]);
        o[dn] = __builtin_amdgcn_mfma_f32_16x16x32_bf16(pf, vf, o[dn], 0, 0, 0);
      }
    }
    __syncthreads();
  }

  // epilogue
#pragma unroll
  for (int r = 0; r < 4; ++r) {
    float inv = 1.0f / lrow[r];
    int row = w * 16 + gq * 4 + r;
#pragma unroll
    for (int dn = 0; dn < 8; ++dn) {
      int col = h * HDIM + dn * 16 + cl;
      O[((size_t)b * SS + q0 + row) * DD + col] = f2bf(o[dn][r] * inv);
    }
  }
}

extern "C" void kernel_launch(void* const* d_in, const int* in_sizes, int n_in,
                              void* d_out, int out_size, void* d_ws, size_t ws_size,
                              hipStream_t stream) {
  const float* x = (const float*)d_in[0];
  const float* Wq = (const float*)d_in[1];
  const float* Wk = (const float*)d_in[2];
  const float* Wv = (const float*)d_in[3];
  const float* Wo = (const float*)d_in[4];
  const float* fc = (const float*)d_in[5];
  const float* fs = (const float*)d_in[6];
  float* out = (float*)d_out;
  char* ws = (char*)d_ws;

  short* xb  = (short*)(ws + 0);                      // 16 MB; later reused as Vt
  short* WqT = (short*)(ws + (size_t)16 * 1048576);
  short* WkT = (short*)(ws + (size_t)24 * 1048576);
  short* WvT = (short*)(ws + (size_t)32 * 1048576);
  short* WoT = (short*)(ws + (size_t)40 * 1048576);
  short* Qb  = (short*)(ws + (size_t)48 * 1048576);
  short* Kb  = (short*)(ws + (size_t)64 * 1048576);
  short* Vb  = (short*)(ws + (size_t)80 * 1048576);   // later reused as attn_out

  cast_bf16_kernel<<<8192, 256, 0, stream>>>(x, xb, 2097152);
  dim3 tg(32, 32);
  transpose_cast_kernel<<<tg, 256, 0, stream>>>(Wq, WqT);
  transpose_cast_kernel<<<tg, 256, 0, stream>>>(Wk, WkT);
  transpose_cast_kernel<<<tg, 256, 0, stream>>>(Wv, WvT);
  transpose_cast_kernel<<<tg, 256, 0, stream>>>(Wo, WoT);

  dim3 gg(16, 32);  // (N/128, M/128)
  gemm_kernel<short><<<gg, 256, 0, stream>>>(xb, WqT, Qb, MM, DD, DD);
  gemm_kernel<short><<<gg, 256, 0, stream>>>(xb, WkT, Kb, MM, DD, DD);
  gemm_kernel<short><<<gg, 256, 0, stream>>>(xb, WvT, Vb, MM, DD, DD);

  rope_kernel<<<4096, 256, 0, stream>>>(Qb, Kb, fc, fs);
  transpose_v_kernel<<<dim3(32, 2, 32), 256, 0, stream>>>(Vb, xb);  // Vt = xb

  attn_kernel<<<dim3(32, 32), 256, 0, stream>>>(Qb, Kb, xb, Vb);    // attn_out = Vb

  gemm_kernel<float><<<gg, 256, 0, stream>>>(Vb, WoT, out, MM, DD, DD);
}

// Round 2
// 347.197 us; speedup vs baseline: 1.1317x; 1.1317x over previous
//
#include <hip/hip_runtime.h>
#include <cstdint>

#define BB 2
#define SS 2048
#define DD 2048
#define HH 16
#define HDIM 128
#define MM (BB * SS)  // 4096

typedef __attribute__((ext_vector_type(8))) short bf16x8;
typedef __attribute__((ext_vector_type(4))) short bf16x4;
typedef __attribute__((ext_vector_type(4))) float f32x4;
typedef __attribute__((ext_vector_type(16))) float f32x16;

__device__ inline short f2bf(float f) {
  union { float f; unsigned u; } v; v.f = f;
  unsigned r = v.u + 0x7FFFu + ((v.u >> 16) & 1u);
  return (short)(r >> 16);
}
__device__ inline float bf2f(short s) {
  union { float f; unsigned u; } v;
  v.u = ((unsigned)(unsigned short)s) << 16;
  return v.f;
}
__device__ inline float asf(int u) { union { int i; float f; } v; v.i = u; return v.f; }
__device__ inline int asi(float f) { union { float f; int i; } v; v.f = f; return v.i; }

__device__ inline unsigned cvtpk_bf16(float lo, float hi) {
  unsigned r;
  asm("v_cvt_pk_bf16_f32 %0, %1, %2" : "=v"(r) : "v"(lo), "v"(hi));
  return r;
}

__device__ inline void gll16(const void* g, void* l) {
  __builtin_amdgcn_global_load_lds(
      (const __attribute__((address_space(1))) void*)g,
      (__attribute__((address_space(3))) void*)l, 16, 0, 0);
}

// ---------------- cast fp32 -> bf16 ----------------
__global__ __launch_bounds__(256) void cast_bf16_kernel(
    const float* __restrict__ x, short* __restrict__ y, int n4) {
  int i = blockIdx.x * 256 + threadIdx.x;
  if (i >= n4) return;
  float4 v = reinterpret_cast<const float4*>(x)[i];
  bf16x4 o;
  o[0] = f2bf(v.x); o[1] = f2bf(v.y); o[2] = f2bf(v.z); o[3] = f2bf(v.w);
  reinterpret_cast<bf16x4*>(y)[i] = o;
}

// ---------------- transpose+cast weight (K,N)fp32 -> (N,K)bf16 ----------------
__global__ __launch_bounds__(256) void transpose_cast_kernel(
    const float* __restrict__ W, short* __restrict__ Wt) {
  __shared__ short tile[64][65];
  int c = threadIdx.x & 63, r4 = threadIdx.x >> 6;
  int n0 = blockIdx.x << 6, k0 = blockIdx.y << 6;
#pragma unroll
  for (int p = 0; p < 16; ++p) {
    int r = (p << 2) + r4;
    tile[c][r] = f2bf(W[(size_t)(k0 + r) * DD + n0 + c]);
  }
  __syncthreads();
#pragma unroll
  for (int p = 0; p < 16; ++p) {
    int r = (p << 2) + r4;
    Wt[(size_t)(n0 + r) * DD + k0 + c] = tile[r][c];
  }
}

// ---------------- transpose V (B,S,D) bf16 head-slices -> Vt (B*H, 128, S) ----------------
__global__ __launch_bounds__(256) void transpose_v_kernel(
    const short* __restrict__ V, short* __restrict__ Vt) {
  __shared__ short tile[64][65];
  int c = threadIdx.x & 63, r4 = threadIdx.x >> 6;
  int s0 = blockIdx.x << 6, d0 = blockIdx.y << 6;
  int bh = blockIdx.z;
  int b = bh >> 4, h = bh & 15;
#pragma unroll
  for (int p = 0; p < 16; ++p) {
    int r = (p << 2) + r4;  // s-local
    tile[c][r] = V[(size_t)(b * SS + s0 + r) * DD + h * HDIM + d0 + c];
  }
  __syncthreads();
#pragma unroll
  for (int p = 0; p < 16; ++p) {
    int r = (p << 2) + r4;  // d-local
    Vt[((size_t)bh * HDIM + d0 + r) * SS + s0 + c] = tile[r][c];
  }
}

// ---------------- RoPE in-place on Q and K (bf16); Q pre-scaled by 1/sqrt(HD) ----------------
__global__ __launch_bounds__(256) void rope_kernel(
    short* __restrict__ Q, short* __restrict__ K,
    const float* __restrict__ fc, const float* __restrict__ fs) {
  int idx = blockIdx.x * 256 + threadIdx.x;  // MM * 256 total
  int m = idx >> 8;
  int c8 = idx & 255;            // 8-elem chunk within row
  int s = m & (SS - 1);
  int i0 = (c8 & 15) << 2;       // pair index base within head
  const float QS = 0.08838834764831845f;  // 1/sqrt(128)
  float4 c4 = *reinterpret_cast<const float4*>(&fc[s * 64 + i0]);
  float4 s4 = *reinterpret_cast<const float4*>(&fs[s * 64 + i0]);
  float cc[4] = {c4.x, c4.y, c4.z, c4.w};
  float sn[4] = {s4.x, s4.y, s4.z, s4.w};
  size_t off = (size_t)m * DD + (c8 << 3);
  {
    bf16x8 v = *reinterpret_cast<bf16x8*>(&Q[off]);
    bf16x8 o;
#pragma unroll
    for (int p = 0; p < 4; ++p) {
      float e = bf2f(v[2 * p]), od = bf2f(v[2 * p + 1]);
      o[2 * p] = f2bf((e * cc[p] - od * sn[p]) * QS);
      o[2 * p + 1] = f2bf((e * sn[p] + od * cc[p]) * QS);
    }
    *reinterpret_cast<bf16x8*>(&Q[off]) = o;
  }
  {
    bf16x8 v = *reinterpret_cast<bf16x8*>(&K[off]);
    bf16x8 o;
#pragma unroll
    for (int p = 0; p < 4; ++p) {
      float e = bf2f(v[2 * p]), od = bf2f(v[2 * p + 1]);
      o[2 * p] = f2bf(e * cc[p] - od * sn[p]);
      o[2 * p + 1] = f2bf(e * sn[p] + od * cc[p]);
    }
    *reinterpret_cast<bf16x8*>(&K[off]) = o;
  }
}

// ---------------- GEMM: C(M,N) = A(M,K) * Bt(N,K)^T, bf16 in, OT out ----------------
template <typename OT>
__global__ __launch_bounds__(256) void gemm_kernel(
    const short* __restrict__ A, const short* __restrict__ Bt, OT* __restrict__ C,
    int Mdim, int Ndim, int Kdim) {
  __shared__ short As[128 * 64];
  __shared__ short Bs[128 * 64];
  int tid = threadIdx.x;
  int lane = tid & 63, w = tid >> 6;
  int cl = lane & 15, gq = lane >> 4;
  int wm = w >> 1, wn = w & 1;
  int m0 = blockIdx.y << 7, n0 = blockIdx.x << 7;
  f32x4 acc[4][4];
#pragma unroll
  for (int i = 0; i < 4; ++i)
#pragma unroll
    for (int j = 0; j < 4; ++j) {
      f32x4 z = {0.f, 0.f, 0.f, 0.f};
      acc[i][j] = z;
    }
  int lrow = lane >> 3;                // 0..7 within 8-row group
  int lseg = (lane & 7) ^ lrow;        // pre-swizzled source segment

  for (int k0 = 0; k0 < Kdim; k0 += 64) {
#pragma unroll
    for (int i = 0; i < 4; ++i) {
      int r0 = ((w << 2) + i) << 3;    // 8-row group base
      gll16(&A[(size_t)(m0 + r0 + lrow) * Kdim + k0 + (lseg << 3)], &As[r0 << 6]);
      gll16(&Bt[(size_t)(n0 + r0 + lrow) * Kdim + k0 + (lseg << 3)], &Bs[r0 << 6]);
    }
    __syncthreads();
#pragma unroll
    for (int ks = 0; ks < 2; ++ks) {
      bf16x8 af[4], bfr[4];
#pragma unroll
      for (int f = 0; f < 4; ++f) {
        int ra = (wm << 6) + (f << 4) + cl;
        af[f] = *reinterpret_cast<const bf16x8*>(
            &As[((ra << 6) + (ks << 5) + (gq << 3)) ^ ((ra & 7) << 3)]);
        int rb = (wn << 6) + (f << 4) + cl;
        bfr[f] = *reinterpret_cast<const bf16x8*>(
            &Bs[((rb << 6) + (ks << 5) + (gq << 3)) ^ ((rb & 7) << 3)]);
      }
#pragma unroll
      for (int fm = 0; fm < 4; ++fm)
#pragma unroll
        for (int fn = 0; fn < 4; ++fn)
          acc[fm][fn] = __builtin_amdgcn_mfma_f32_16x16x32_bf16(
              af[fm], bfr[fn], acc[fm][fn], 0, 0, 0);
    }
    __syncthreads();
  }
#pragma unroll
  for (int fm = 0; fm < 4; ++fm)
#pragma unroll
    for (int r = 0; r < 4; ++r) {
      int mrow = m0 + (wm << 6) + (fm << 4) + (gq << 2) + r;
#pragma unroll
      for (int fn = 0; fn < 4; ++fn) {
        int ncol = n0 + (wn << 6) + (fn << 4) + cl;
        float vv = acc[fm][fn][r];
        if constexpr (sizeof(OT) == 2)
          C[(size_t)mrow * Ndim + ncol] = (OT)f2bf(vv);
        else
          C[(size_t)mrow * Ndim + ncol] = vv;
      }
    }
}

// ---------------- flash attention, swapped-QK^T 32x32 structure ----------------
// grid: 512 blocks 1-D, descending-work order: qi = 15 - (id>>5), bh = id&31.
// 4 waves x QBLK=32 q-rows = 128 q-rows per block; KVBLK = 64.
// QK^T computed transposed: S^T = K·Q^T  (lane holds P column for q = lane&31)
// PV computed transposed:   O^T = V^T·P^T (lane's accum column is its own q row)
__global__ __launch_bounds__(256, 2) void attn_kernel(
    const short* __restrict__ Q, const short* __restrict__ K,
    const short* __restrict__ Vt, short* __restrict__ O) {
  __shared__ short Kl[64 * 128];   // [kv][d], 3-bit XOR seg swizzle
  __shared__ short Vl[128 * 64];   // [d][kv], 3-bit XOR seg swizzle
  const int id = blockIdx.x;
  const int qi = 15 - (id >> 5);   // heavy blocks dispatched first
  const int bh = id & 31;
  const int b = bh >> 4, h = bh & 15;
  const int tid = threadIdx.x;
  const int lane = tid & 63, w = tid >> 6;
  const int l31 = lane & 31, hi = lane >> 5;
  const int qw = qi * 128 + w * 32;   // wave's q base
  const int qg = qw + l31;            // this lane's q row

  // Q fragments hoisted: Q pre-scaled by 1/sqrt(HD) in rope.
  // B-frag (32x32x16): col = lane&31 (q), k = hi*8+j; 8 d-steps of 16.
  bf16x8 qf[8];
  const size_t qoff = ((size_t)b * SS + qg) * DD + h * HDIM;
#pragma unroll
  for (int s = 0; s < 8; ++s)
    qf[s] = *reinterpret_cast<const bf16x8*>(&Q[qoff + s * 16 + hi * 8]);

  f32x16 ot[4];
#pragma unroll
  for (int dt = 0; dt < 4; ++dt)
#pragma unroll
    for (int r = 0; r < 16; ++r) ot[dt][r] = 0.f;
  float m_run = -INFINITY, l_run = 0.f;

  const int NT = 2 * qi + 2;
  for (int t = 0; t < NT; ++t) {
    // ---- stage K [64][128] and V^T [128][64] into LDS, swizzled ----
#pragma unroll
    for (int it = 0; it < 4; ++it) {
      int id2 = it * 256 + tid;
      int kr = id2 >> 4, sg = id2 & 15;
      bf16x8 kv = *reinterpret_cast<const bf16x8*>(
          &K[((size_t)b * SS + t * 64 + kr) * DD + h * HDIM + sg * 8]);
      *reinterpret_cast<bf16x8*>(&Kl[kr * 128 + ((sg ^ (kr & 7)) << 3)]) = kv;
      int vd = id2 >> 3, vs = id2 & 7;
      bf16x8 vv = *reinterpret_cast<const bf16x8*>(
          &Vt[((size_t)bh * HDIM + vd) * SS + t * 64 + vs * 8]);
      *reinterpret_cast<bf16x8*>(&Vl[vd * 64 + ((vs ^ (vd & 7)) << 3)]) = vv;
    }
    __syncthreads();

    if (t * 64 <= qw + 31) {  // wave has unmasked work in this kv tile
      // ---- S^T = K · Q^T : two 32-row kv tiles, 8 k-steps of d=16 ----
      f32x16 st0, st1;
#pragma unroll
      for (int r = 0; r < 16; ++r) { st0[r] = 0.f; st1[r] = 0.f; }
#pragma unroll
      for (int s = 0; s < 8; ++s) {
        const int cs = (s * 2 + hi);
        bf16x8 kf0 = *reinterpret_cast<const bf16x8*>(
            &Kl[l31 * 128 + ((cs ^ (l31 & 7)) << 3)]);
        st0 = __builtin_amdgcn_mfma_f32_32x32x16_bf16(kf0, qf[s], st0, 0, 0, 0);
        bf16x8 kf1 = *reinterpret_cast<const bf16x8*>(
            &Kl[(32 + l31) * 128 + ((cs ^ (l31 & 7)) << 3)]);
        st1 = __builtin_amdgcn_mfma_f32_32x32x16_bf16(kf1, qf[s], st1, 0, 0, 0);
      }
      // ---- causal mask (only near-diagonal tiles) ----
      if (t * 64 + 63 > qw) {
#pragma unroll
        for (int r = 0; r < 16; ++r) {
          int dl = (r & 3) + 8 * (r >> 2) + 4 * hi;  // kv row within 32-tile
          if (t * 64 + dl > qg) st0[r] = -1e30f;
          if (t * 64 + 32 + dl > qg) st1[r] = -1e30f;
        }
      }
      // ---- in-register online softmax (per-lane row; combine halves via swap) ----
      float pm = st0[0];
#pragma unroll
      for (int r = 1; r < 16; ++r) pm = fmaxf(pm, st0[r]);
#pragma unroll
      for (int r = 0; r < 16; ++r) pm = fmaxf(pm, st1[r]);
      {
        auto sw = __builtin_amdgcn_permlane32_swap(asi(pm), asi(pm), false, false);
        pm = fmaxf(asf(sw[0]), asf(sw[1]));
      }
      float mn = fmaxf(m_run, pm);
      float al = __expf(m_run - mn);
      m_run = mn;
      float p[32];
      float ps = 0.f;
#pragma unroll
      for (int r = 0; r < 16; ++r) { p[r] = __expf(st0[r] - mn); ps += p[r]; }
#pragma unroll
      for (int r = 0; r < 16; ++r) { p[16 + r] = __expf(st1[r] - mn); ps += p[16 + r]; }
      {
        auto sw = __builtin_amdgcn_permlane32_swap(asi(ps), asi(ps), false, false);
        ps = asf(sw[0]) + asf(sw[1]);
      }
      l_run = l_run * al + ps;
#pragma unroll
      for (int dt = 0; dt < 4; ++dt)
#pragma unroll
        for (int r = 0; r < 16; ++r) ot[dt][r] *= al;

      // ---- pack P -> bf16 B-frags via cvt_pk + permlane32_swap (T12) ----
      bf16x8 pf[4];
#pragma unroll
      for (int s = 0; s < 4; ++s) {
        unsigned a0 = cvtpk_bf16(p[8 * s + 0], p[8 * s + 1]);
        unsigned a1 = cvtpk_bf16(p[8 * s + 2], p[8 * s + 3]);
        unsigned b0 = cvtpk_bf16(p[8 * s + 4], p[8 * s + 5]);
        unsigned b1 = cvtpk_bf16(p[8 * s + 6], p[8 * s + 7]);
        auto r0 = __builtin_amdgcn_permlane32_swap((int)a0, (int)b0, false, false);
        auto r1 = __builtin_amdgcn_permlane32_swap((int)a1, (int)b1, false, false);
        union { int u[4]; bf16x8 v; } pk;
        pk.u[0] = r0[0]; pk.u[1] = r1[0]; pk.u[2] = r0[1]; pk.u[3] = r1[1];
        pf[s] = pk.v;
      }

      // ---- O^T += V^T · P^T : 4 d-tiles x 4 kv-steps of 16 ----
#pragma unroll
      for (int dt = 0; dt < 4; ++dt) {
        const int vr = dt * 32 + l31;
#pragma unroll
        for (int s = 0; s < 4; ++s) {
          bf16x8 vf = *reinterpret_cast<const bf16x8*>(
              &Vl[vr * 64 + (((s * 2 + hi) ^ (vr & 7)) << 3)]);
          ot[dt] = __builtin_amdgcn_mfma_f32_32x32x16_bf16(vf, pf[s], ot[dt], 0, 0, 0);
        }
      }
    }
    __syncthreads();
  }

  // ---- epilogue: lane's accum column is q = lane&31; d rows = crow(r,hi) ----
  float inv = 1.0f / l_run;
  const size_t orow = ((size_t)b * SS + qg) * DD + h * HDIM;
#pragma unroll
  for (int dt = 0; dt < 4; ++dt)
#pragma unroll
    for (int g = 0; g < 4; ++g) {
      bf16x4 v;
#pragma unroll
      for (int k = 0; k < 4; ++k) v[k] = f2bf(ot[dt][4 * g + k] * inv);
      *reinterpret_cast<bf16x4*>(&O[orow + dt * 32 + 8 * g + 4 * hi]) = v;
    }
}

extern "C" void kernel_launch(void* const* d_in, const int* in_sizes, int n_in,
                              void* d_out, int out_size, void* d_ws, size_t ws_size,
                              hipStream_t stream) {
  const float* x = (const float*)d_in[0];
  const float* Wq = (const float*)d_in[1];
  const float* Wk = (const float*)d_in[2];
  const float* Wv = (const float*)d_in[3];
  const float* Wo = (const float*)d_in[4];
  const float* fc = (const float*)d_in[5];
  const float* fs = (const float*)d_in[6];
  float* out = (float*)d_out;
  char* ws = (char*)d_ws;

  short* xb  = (short*)(ws + 0);                      // 16 MB; later reused as Vt
  short* WqT = (short*)(ws + (size_t)16 * 1048576);
  short* WkT = (short*)(ws + (size_t)24 * 1048576);
  short* WvT = (short*)(ws + (size_t)32 * 1048576);
  short* WoT = (short*)(ws + (size_t)40 * 1048576);
  short* Qb  = (short*)(ws + (size_t)48 * 1048576);
  short* Kb  = (short*)(ws + (size_t)64 * 1048576);
  short* Vb  = (short*)(ws + (size_t)80 * 1048576);   // later reused as attn_out

  cast_bf16_kernel<<<8192, 256, 0, stream>>>(x, xb, 2097152);
  dim3 tg(32, 32);
  transpose_cast_kernel<<<tg, 256, 0, stream>>>(Wq, WqT);
  transpose_cast_kernel<<<tg, 256, 0, stream>>>(Wk, WkT);
  transpose_cast_kernel<<<tg, 256, 0, stream>>>(Wv, WvT);
  transpose_cast_kernel<<<tg, 256, 0, stream>>>(Wo, WoT);

  dim3 gg(16, 32);  // (N/128, M/128)
  gemm_kernel<short><<<gg, 256, 0, stream>>>(xb, WqT, Qb, MM, DD, DD);
  gemm_kernel<short><<<gg, 256, 0, stream>>>(xb, WkT, Kb, MM, DD, DD);
  gemm_kernel<short><<<gg, 256, 0, stream>>>(xb, WvT, Vb, MM, DD, DD);

  rope_kernel<<<4096, 256, 0, stream>>>(Qb, Kb, fc, fs);
  transpose_v_kernel<<<dim3(32, 2, 32), 256, 0, stream>>>(Vb, xb);  // Vt = xb

  attn_kernel<<<512, 256, 0, stream>>>(Qb, Kb, xb, Vb);             // attn_out = Vb

  gemm_kernel<float><<<gg, 256, 0, stream>>>(Vb, WoT, out, MM, DD, DD);
}

// Round 3
// 293.494 us; speedup vs baseline: 1.3387x; 1.1830x over previous
//
#include <hip/hip_runtime.h>
#include <cstdint>

#define BB 2
#define SS 2048
#define DD 2048
#define HH 16
#define HDIM 128
#define MM (BB * SS)  // 4096

typedef __attribute__((ext_vector_type(8))) short bf16x8;
typedef __attribute__((ext_vector_type(4))) short bf16x4;
typedef __attribute__((ext_vector_type(4))) float f32x4;
typedef __attribute__((ext_vector_type(16))) float f32x16;

__device__ inline short f2bf(float f) {
  union { float f; unsigned u; } v; v.f = f;
  unsigned r = v.u + 0x7FFFu + ((v.u >> 16) & 1u);
  return (short)(r >> 16);
}
__device__ inline float bf2f(short s) {
  union { float f; unsigned u; } v;
  v.u = ((unsigned)(unsigned short)s) << 16;
  return v.f;
}
__device__ inline float asf(int u) { union { int i; float f; } v; v.i = u; return v.f; }
__device__ inline int asi(float f) { union { float f; int i; } v; v.f = f; return v.i; }

__device__ inline unsigned cvtpk_bf16(float lo, float hi) {
  unsigned r;
  asm("v_cvt_pk_bf16_f32 %0, %1, %2" : "=v"(r) : "v"(lo), "v"(hi));
  return r;
}

__device__ inline void gll16(const void* g, void* l) {
  __builtin_amdgcn_global_load_lds(
      (const __attribute__((address_space(1))) void*)g,
      (__attribute__((address_space(3))) void*)l, 16, 0, 0);
}

// ---------------- cast fp32 -> bf16 ----------------
__global__ __launch_bounds__(256) void cast_bf16_kernel(
    const float* __restrict__ x, short* __restrict__ y, int n4) {
  int i = blockIdx.x * 256 + threadIdx.x;
  if (i >= n4) return;
  float4 v = reinterpret_cast<const float4*>(x)[i];
  bf16x4 o;
  o[0] = f2bf(v.x); o[1] = f2bf(v.y); o[2] = f2bf(v.z); o[3] = f2bf(v.w);
  reinterpret_cast<bf16x4*>(y)[i] = o;
}

// ---------------- transpose+cast weight (K,N)fp32 -> (N,K)bf16 ----------------
__global__ __launch_bounds__(256) void transpose_cast_kernel(
    const float* __restrict__ W, short* __restrict__ Wt) {
  __shared__ short tile[64][65];
  int c = threadIdx.x & 63, r4 = threadIdx.x >> 6;
  int n0 = blockIdx.x << 6, k0 = blockIdx.y << 6;
#pragma unroll
  for (int p = 0; p < 16; ++p) {
    int r = (p << 2) + r4;
    tile[c][r] = f2bf(W[(size_t)(k0 + r) * DD + n0 + c]);
  }
  __syncthreads();
#pragma unroll
  for (int p = 0; p < 16; ++p) {
    int r = (p << 2) + r4;
    Wt[(size_t)(n0 + r) * DD + k0 + c] = tile[r][c];
  }
}

// ---------------- transpose V (B,S,D) bf16 head-slices -> Vt (B*H, 128, S) ----------------
__global__ __launch_bounds__(256) void transpose_v_kernel(
    const short* __restrict__ V, short* __restrict__ Vt) {
  __shared__ short tile[64][65];
  int c = threadIdx.x & 63, r4 = threadIdx.x >> 6;
  int s0 = blockIdx.x << 6, d0 = blockIdx.y << 6;
  int bh = blockIdx.z;
  int b = bh >> 4, h = bh & 15;
#pragma unroll
  for (int p = 0; p < 16; ++p) {
    int r = (p << 2) + r4;  // s-local
    tile[c][r] = V[(size_t)(b * SS + s0 + r) * DD + h * HDIM + d0 + c];
  }
  __syncthreads();
#pragma unroll
  for (int p = 0; p < 16; ++p) {
    int r = (p << 2) + r4;  // d-local
    Vt[((size_t)bh * HDIM + d0 + r) * SS + s0 + c] = tile[r][c];
  }
}

// ---------------- RoPE in-place on Q and K (bf16); Q pre-scaled by 1/sqrt(HD) ----------------
__global__ __launch_bounds__(256) void rope_kernel(
    short* __restrict__ Q, short* __restrict__ K,
    const float* __restrict__ fc, const float* __restrict__ fs) {
  int idx = blockIdx.x * 256 + threadIdx.x;  // MM * 256 total
  int m = idx >> 8;
  int c8 = idx & 255;            // 8-elem chunk within row
  int s = m & (SS - 1);
  int i0 = (c8 & 15) << 2;       // pair index base within head
  const float QS = 0.08838834764831845f;  // 1/sqrt(128)
  float4 c4 = *reinterpret_cast<const float4*>(&fc[s * 64 + i0]);
  float4 s4 = *reinterpret_cast<const float4*>(&fs[s * 64 + i0]);
  float cc[4] = {c4.x, c4.y, c4.z, c4.w};
  float sn[4] = {s4.x, s4.y, s4.z, s4.w};
  size_t off = (size_t)m * DD + (c8 << 3);
  {
    bf16x8 v = *reinterpret_cast<bf16x8*>(&Q[off]);
    bf16x8 o;
#pragma unroll
    for (int p = 0; p < 4; ++p) {
      float e = bf2f(v[2 * p]), od = bf2f(v[2 * p + 1]);
      o[2 * p] = f2bf((e * cc[p] - od * sn[p]) * QS);
      o[2 * p + 1] = f2bf((e * sn[p] + od * cc[p]) * QS);
    }
    *reinterpret_cast<bf16x8*>(&Q[off]) = o;
  }
  {
    bf16x8 v = *reinterpret_cast<bf16x8*>(&K[off]);
    bf16x8 o;
#pragma unroll
    for (int p = 0; p < 4; ++p) {
      float e = bf2f(v[2 * p]), od = bf2f(v[2 * p + 1]);
      o[2 * p] = f2bf(e * cc[p] - od * sn[p]);
      o[2 * p + 1] = f2bf(e * sn[p] + od * cc[p]);
    }
    *reinterpret_cast<bf16x8*>(&K[off]) = o;
  }
}

// ---------------- GEMM: C(M,N) = A(M,K) * Bt(N,K)^T, bf16 in, OT out ----------------
template <typename OT>
__global__ __launch_bounds__(256) void gemm_kernel(
    const short* __restrict__ A, const short* __restrict__ Bt, OT* __restrict__ C,
    int Mdim, int Ndim, int Kdim) {
  __shared__ short As[128 * 64];
  __shared__ short Bs[128 * 64];
  int tid = threadIdx.x;
  int lane = tid & 63, w = tid >> 6;
  int cl = lane & 15, gq = lane >> 4;
  int wm = w >> 1, wn = w & 1;
  int m0 = blockIdx.y << 7, n0 = blockIdx.x << 7;
  f32x4 acc[4][4];
#pragma unroll
  for (int i = 0; i < 4; ++i)
#pragma unroll
    for (int j = 0; j < 4; ++j) {
      f32x4 z = {0.f, 0.f, 0.f, 0.f};
      acc[i][j] = z;
    }
  int lrow = lane >> 3;                // 0..7 within 8-row group
  int lseg = (lane & 7) ^ lrow;        // pre-swizzled source segment

  for (int k0 = 0; k0 < Kdim; k0 += 64) {
#pragma unroll
    for (int i = 0; i < 4; ++i) {
      int r0 = ((w << 2) + i) << 3;    // 8-row group base
      gll16(&A[(size_t)(m0 + r0 + lrow) * Kdim + k0 + (lseg << 3)], &As[r0 << 6]);
      gll16(&Bt[(size_t)(n0 + r0 + lrow) * Kdim + k0 + (lseg << 3)], &Bs[r0 << 6]);
    }
    __syncthreads();
#pragma unroll
    for (int ks = 0; ks < 2; ++ks) {
      bf16x8 af[4], bfr[4];
#pragma unroll
      for (int f = 0; f < 4; ++f) {
        int ra = (wm << 6) + (f << 4) + cl;
        af[f] = *reinterpret_cast<const bf16x8*>(
            &As[((ra << 6) + (ks << 5) + (gq << 3)) ^ ((ra & 7) << 3)]);
        int rb = (wn << 6) + (f << 4) + cl;
        bfr[f] = *reinterpret_cast<const bf16x8*>(
            &Bs[((rb << 6) + (ks << 5) + (gq << 3)) ^ ((rb & 7) << 3)]);
      }
#pragma unroll
      for (int fm = 0; fm < 4; ++fm)
#pragma unroll
        for (int fn = 0; fn < 4; ++fn)
          acc[fm][fn] = __builtin_amdgcn_mfma_f32_16x16x32_bf16(
              af[fm], bfr[fn], acc[fm][fn], 0, 0, 0);
    }
    __syncthreads();
  }
#pragma unroll
  for (int fm = 0; fm < 4; ++fm)
#pragma unroll
    for (int r = 0; r < 4; ++r) {
      int mrow = m0 + (wm << 6) + (fm << 4) + (gq << 2) + r;
#pragma unroll
      for (int fn = 0; fn < 4; ++fn) {
        int ncol = n0 + (wn << 6) + (fn << 4) + cl;
        float vv = acc[fm][fn][r];
        if constexpr (sizeof(OT) == 2)
          C[(size_t)mrow * Ndim + ncol] = (OT)f2bf(vv);
        else
          C[(size_t)mrow * Ndim + ncol] = vv;
      }
    }
}

// ---------------- flash attention, swapped-QK^T 32x32, T3-min pipelined ----------------
// grid: 512 blocks, LPT order (heavy first): qi = 15 - (id>>5), bh = id&31.
// 4 waves x 32 q-rows = 128 q-rows per block; KVBLK = 64.
// S^T = K*Q^T (lane holds P column for q = lane&31); O^T = V^T*P^T.
// K/V double-buffered in LDS, staged via global_load_lds with pre-swizzled
// source (linear dest + inverse-swizzled source + swizzled read; rule #21).
__global__ __launch_bounds__(256, 2) void attn_kernel(
    const short* __restrict__ Q, const short* __restrict__ K,
    const short* __restrict__ Vt, short* __restrict__ O) {
  __shared__ short Kl[2][64 * 128];   // 16KB each, [kv][d] 3-bit XOR seg swizzle
  __shared__ short Vl[2][128 * 64];   // 16KB each, [d][kv] 3-bit XOR seg swizzle
  const int id = blockIdx.x;
  const int qi = 15 - (id >> 5);      // heavy blocks dispatched first
  const int bh = id & 31;
  const int b = bh >> 4, h = bh & 15;
  const int tid = threadIdx.x;
  const int lane = tid & 63, w = tid >> 6;
  const int l31 = lane & 31, hi = lane >> 5;
  const int qw = qi * 128 + w * 32;   // wave's q base
  const int qg = qw + l31;            // this lane's q row

  // staging geometry: 16KB tile = 16 x 1KB gll chunks, 4 chunks per wave.
  // K chunk c: rows c*4+(lane>>4), phys seg lane&15, semantic seg = pseg^(r&7)
  // V chunk c: d rows c*8+(lane>>3), phys seg lane&7, semantic seg = pseg^(d&7)
  const short* Kbase = K + (size_t)b * SS * DD + h * HDIM;
  const short* Vbase = Vt + (size_t)bh * HDIM * SS;
  int krow[4], kq[4], vd[4], vs[4];
#pragma unroll
  for (int i = 0; i < 4; ++i) {
    int c = w * 4 + i;
    krow[i] = c * 4 + (lane >> 4);
    kq[i] = (lane & 15) ^ (krow[i] & 7);
    vd[i] = c * 8 + (lane >> 3);
    vs[i] = (lane & 7) ^ (vd[i] & 7);
  }

  // Q fragments hoisted; Q pre-scaled by 1/sqrt(HD) in rope.
  bf16x8 qf[8];
  const size_t qoff = ((size_t)b * SS + qg) * DD + h * HDIM;
#pragma unroll
  for (int s = 0; s < 8; ++s)
    qf[s] = *reinterpret_cast<const bf16x8*>(&Q[qoff + s * 16 + hi * 8]);

  f32x16 ot[4];
#pragma unroll
  for (int dt = 0; dt < 4; ++dt)
#pragma unroll
    for (int r = 0; r < 16; ++r) ot[dt][r] = 0.f;
  float m_run = -INFINITY, l_run = 0.f;

  const int NT = 2 * qi + 2;

  // prologue: stage tile 0 into buf 0
#pragma unroll
  for (int i = 0; i < 4; ++i) {
    gll16(Kbase + (size_t)krow[i] * DD + kq[i] * 8, &Kl[0][(w * 4 + i) * 512]);
    gll16(Vbase + (size_t)vd[i] * SS + vs[i] * 8, &Vl[0][(w * 4 + i) * 512]);
  }
  __syncthreads();

  for (int t = 0; t < NT; ++t) {
    const int cur = t & 1;
    // issue next tile's staging into the other buffer (flies during compute)
    if (t + 1 < NT) {
      const int nt64 = (t + 1) * 64;
#pragma unroll
      for (int i = 0; i < 4; ++i) {
        gll16(Kbase + (size_t)(nt64 + krow[i]) * DD + kq[i] * 8,
              &Kl[cur ^ 1][(w * 4 + i) * 512]);
        gll16(Vbase + (size_t)vd[i] * SS + nt64 + vs[i] * 8,
              &Vl[cur ^ 1][(w * 4 + i) * 512]);
      }
    }

    if (t * 64 <= qw + 31) {  // wave has unmasked work in this kv tile
      const short* Kc = Kl[cur];
      const short* Vc = Vl[cur];
      // ---- S^T = K * Q^T : two 32-row kv tiles, 8 k-steps of d=16 ----
      f32x16 st0, st1;
#pragma unroll
      for (int r = 0; r < 16; ++r) { st0[r] = 0.f; st1[r] = 0.f; }
      __builtin_amdgcn_s_setprio(1);
#pragma unroll
      for (int s = 0; s < 8; ++s) {
        const int cs = (s * 2 + hi);
        bf16x8 kf0 = *reinterpret_cast<const bf16x8*>(
            &Kc[l31 * 128 + ((cs ^ (l31 & 7)) << 3)]);
        st0 = __builtin_amdgcn_mfma_f32_32x32x16_bf16(kf0, qf[s], st0, 0, 0, 0);
        bf16x8 kf1 = *reinterpret_cast<const bf16x8*>(
            &Kc[(32 + l31) * 128 + ((cs ^ (l31 & 7)) << 3)]);
        st1 = __builtin_amdgcn_mfma_f32_32x32x16_bf16(kf1, qf[s], st1, 0, 0, 0);
      }
      __builtin_amdgcn_s_setprio(0);
      // ---- causal mask (only near-diagonal tiles) ----
      if (t * 64 + 63 > qw) {
#pragma unroll
        for (int r = 0; r < 16; ++r) {
          int dl = (r & 3) + 8 * (r >> 2) + 4 * hi;  // kv row within 32-tile
          if (t * 64 + dl > qg) st0[r] = -1e30f;
          if (t * 64 + 32 + dl > qg) st1[r] = -1e30f;
        }
      }
      // ---- online softmax, in-register; defer-max (T13, THR=8) ----
      float pm = st0[0];
#pragma unroll
      for (int r = 1; r < 16; ++r) pm = fmaxf(pm, st0[r]);
#pragma unroll
      for (int r = 0; r < 16; ++r) pm = fmaxf(pm, st1[r]);
      {
        auto sw = __builtin_amdgcn_permlane32_swap(asi(pm), asi(pm), false, false);
        pm = fmaxf(asf(sw[0]), asf(sw[1]));
      }
      if (!__all(pm <= m_run + 8.f)) {
        float mn = fmaxf(m_run, pm);
        float al = __expf(m_run - mn);
        m_run = mn;
        l_run *= al;
#pragma unroll
        for (int dt = 0; dt < 4; ++dt)
#pragma unroll
          for (int r = 0; r < 16; ++r) ot[dt][r] *= al;
      }
      float ps = 0.f;
#pragma unroll
      for (int r = 0; r < 16; ++r) { st0[r] = __expf(st0[r] - m_run); ps += st0[r]; }
#pragma unroll
      for (int r = 0; r < 16; ++r) { st1[r] = __expf(st1[r] - m_run); ps += st1[r]; }
      {
        auto sw = __builtin_amdgcn_permlane32_swap(asi(ps), asi(ps), false, false);
        ps = asf(sw[0]) + asf(sw[1]);
      }
      l_run += ps;

      // ---- pack P -> bf16 B-frags via cvt_pk + permlane32_swap (T12) ----
      bf16x8 pf[4];
#pragma unroll
      for (int s = 0; s < 4; ++s) {
        float e0, e1, e2, e3, e4, e5, e6, e7;
        if (s < 2) {
          e0 = st0[8 * s + 0]; e1 = st0[8 * s + 1]; e2 = st0[8 * s + 2]; e3 = st0[8 * s + 3];
          e4 = st0[8 * s + 4]; e5 = st0[8 * s + 5]; e6 = st0[8 * s + 6]; e7 = st0[8 * s + 7];
        } else {
          e0 = st1[8 * (s - 2) + 0]; e1 = st1[8 * (s - 2) + 1]; e2 = st1[8 * (s - 2) + 2]; e3 = st1[8 * (s - 2) + 3];
          e4 = st1[8 * (s - 2) + 4]; e5 = st1[8 * (s - 2) + 5]; e6 = st1[8 * (s - 2) + 6]; e7 = st1[8 * (s - 2) + 7];
        }
        unsigned a0 = cvtpk_bf16(e0, e1);
        unsigned a1 = cvtpk_bf16(e2, e3);
        unsigned b0 = cvtpk_bf16(e4, e5);
        unsigned b1 = cvtpk_bf16(e6, e7);
        auto r0 = __builtin_amdgcn_permlane32_swap((int)a0, (int)b0, false, false);
        auto r1 = __builtin_amdgcn_permlane32_swap((int)a1, (int)b1, false, false);
        union { int u[4]; bf16x8 v; } pk;
        pk.u[0] = r0[0]; pk.u[1] = r1[0]; pk.u[2] = r0[1]; pk.u[3] = r1[1];
        pf[s] = pk.v;
      }

      // ---- O^T += V^T * P^T : 4 d-tiles x 4 kv-steps of 16 ----
      __builtin_amdgcn_s_setprio(1);
#pragma unroll
      for (int dt = 0; dt < 4; ++dt) {
        const int vr = dt * 32 + l31;
#pragma unroll
        for (int s = 0; s < 4; ++s) {
          bf16x8 vf = *reinterpret_cast<const bf16x8*>(
              &Vc[vr * 64 + (((s * 2 + hi) ^ (vr & 7)) << 3)]);
          ot[dt] = __builtin_amdgcn_mfma_f32_32x32x16_bf16(vf, pf[s], ot[dt], 0, 0, 0);
        }
      }
      __builtin_amdgcn_s_setprio(0);
    }
    __syncthreads();  // drains next tile's gll (vmcnt 0) + guards buffer reuse
  }

  // ---- epilogue: lane's accum column is q = lane&31; d rows = crow(r,hi) ----
  float inv = 1.0f / l_run;
  const size_t orow = ((size_t)b * SS + qg) * DD + h * HDIM;
#pragma unroll
  for (int dt = 0; dt < 4; ++dt)
#pragma unroll
    for (int g = 0; g < 4; ++g) {
      bf16x4 v;
#pragma unroll
      for (int k = 0; k < 4; ++k) v[k] = f2bf(ot[dt][4 * g + k] * inv);
      *reinterpret_cast<bf16x4*>(&O[orow + dt * 32 + 8 * g + 4 * hi]) = v;
    }
}

extern "C" void kernel_launch(void* const* d_in, const int* in_sizes, int n_in,
                              void* d_out, int out_size, void* d_ws, size_t ws_size,
                              hipStream_t stream) {
  const float* x = (const float*)d_in[0];
  const float* Wq = (const float*)d_in[1];
  const float* Wk = (const float*)d_in[2];
  const float* Wv = (const float*)d_in[3];
  const float* Wo = (const float*)d_in[4];
  const float* fc = (const float*)d_in[5];
  const float* fs = (const float*)d_in[6];
  float* out = (float*)d_out;
  char* ws = (char*)d_ws;

  short* xb  = (short*)(ws + 0);                      // 16 MB; later reused as Vt
  short* WqT = (short*)(ws + (size_t)16 * 1048576);
  short* WkT = (short*)(ws + (size_t)24 * 1048576);
  short* WvT = (short*)(ws + (size_t)32 * 1048576);
  short* WoT = (short*)(ws + (size_t)40 * 1048576);
  short* Qb  = (short*)(ws + (size_t)48 * 1048576);
  short* Kb  = (short*)(ws + (size_t)64 * 1048576);
  short* Vb  = (short*)(ws + (size_t)80 * 1048576);   // later reused as attn_out

  cast_bf16_kernel<<<8192, 256, 0, stream>>>(x, xb, 2097152);
  dim3 tg(32, 32);
  transpose_cast_kernel<<<tg, 256, 0, stream>>>(Wq, WqT);
  transpose_cast_kernel<<<tg, 256, 0, stream>>>(Wk, WkT);
  transpose_cast_kernel<<<tg, 256, 0, stream>>>(Wv, WvT);
  transpose_cast_kernel<<<tg, 256, 0, stream>>>(Wo, WoT);

  dim3 gg(16, 32);  // (N/128, M/128)
  gemm_kernel<short><<<gg, 256, 0, stream>>>(xb, WqT, Qb, MM, DD, DD);
  gemm_kernel<short><<<gg, 256, 0, stream>>>(xb, WkT, Kb, MM, DD, DD);
  gemm_kernel<short><<<gg, 256, 0, stream>>>(xb, WvT, Vb, MM, DD, DD);

  rope_kernel<<<4096, 256, 0, stream>>>(Qb, Kb, fc, fs);
  transpose_v_kernel<<<dim3(32, 2, 32), 256, 0, stream>>>(Vb, xb);  // Vt = xb

  attn_kernel<<<512, 256, 0, stream>>>(Qb, Kb, xb, Vb);             // attn_out = Vb

  gemm_kernel<float><<<gg, 256, 0, stream>>>(Vb, WoT, out, MM, DD, DD);
}

// Round 4
// 282.571 us; speedup vs baseline: 1.3905x; 1.0387x over previous
//
#include <hip/hip_runtime.h>
#include <cstdint>

#define BB 2
#define SS 2048
#define DD 2048
#define HH 16
#define HDIM 128
#define MM (BB * SS)  // 4096

typedef __attribute__((ext_vector_type(8))) short bf16x8;
typedef __attribute__((ext_vector_type(4))) short bf16x4;
typedef __attribute__((ext_vector_type(4))) float f32x4;
typedef __attribute__((ext_vector_type(16))) float f32x16;

__device__ inline short f2bf(float f) {
  union { float f; unsigned u; } v; v.f = f;
  unsigned r = v.u + 0x7FFFu + ((v.u >> 16) & 1u);
  return (short)(r >> 16);
}
__device__ inline float bf2f(short s) {
  union { float f; unsigned u; } v;
  v.u = ((unsigned)(unsigned short)s) << 16;
  return v.f;
}
__device__ inline float asf(int u) { union { int i; float f; } v; v.i = u; return v.f; }
__device__ inline int asi(float f) { union { float f; int i; } v; v.f = f; return v.i; }

__device__ inline unsigned cvtpk_bf16(float lo, float hi) {
  unsigned r;
  asm("v_cvt_pk_bf16_f32 %0, %1, %2" : "=v"(r) : "v"(lo), "v"(hi));
  return r;
}

__device__ inline void gll16(const void* g, void* l) {
  __builtin_amdgcn_global_load_lds(
      (const __attribute__((address_space(1))) void*)g,
      (__attribute__((address_space(3))) void*)l, 16, 0, 0);
}

// ---------------- cast fp32 -> bf16 ----------------
__global__ __launch_bounds__(256) void cast_bf16_kernel(
    const float* __restrict__ x, short* __restrict__ y, int n4) {
  int i = blockIdx.x * 256 + threadIdx.x;
  if (i >= n4) return;
  float4 v = reinterpret_cast<const float4*>(x)[i];
  bf16x4 o;
  o[0] = f2bf(v.x); o[1] = f2bf(v.y); o[2] = f2bf(v.z); o[3] = f2bf(v.w);
  reinterpret_cast<bf16x4*>(y)[i] = o;
}

// ---------------- transpose+cast weight (K,N)fp32 -> (N,K)bf16 ----------------
__global__ __launch_bounds__(256) void transpose_cast_kernel(
    const float* __restrict__ W, short* __restrict__ Wt) {
  __shared__ short tile[64][65];
  int c = threadIdx.x & 63, r4 = threadIdx.x >> 6;
  int n0 = blockIdx.x << 6, k0 = blockIdx.y << 6;
#pragma unroll
  for (int p = 0; p < 16; ++p) {
    int r = (p << 2) + r4;
    tile[c][r] = f2bf(W[(size_t)(k0 + r) * DD + n0 + c]);
  }
  __syncthreads();
#pragma unroll
  for (int p = 0; p < 16; ++p) {
    int r = (p << 2) + r4;
    Wt[(size_t)(n0 + r) * DD + k0 + c] = tile[r][c];
  }
}

// ---------------- fused QKV GEMM: C(4096,6144) = xb * WqkvT^T ----------------
// 128x128 tile, BK=64, 4 waves. Per-block epilogue by n-range:
//   mat 0 (Q): RoPE + scale by (1/sqrt(128))*log2(e), write Qb bf16
//   mat 1 (K): RoPE, write Kb bf16
//   mat 2 (V): 128x128 LDS transpose, write Vt (B*H,128,S) bf16
__global__ __launch_bounds__(256) void qkv_gemm_kernel(
    const short* __restrict__ A, const short* __restrict__ Bt,
    short* __restrict__ Qb, short* __restrict__ Kb, short* __restrict__ Vt,
    const float* __restrict__ fc, const float* __restrict__ fs) {
  __shared__ short smem[128 * 136];  // As(8192 shorts)+Bs(8192); epilogue reuses as Tt
  short* As = smem;
  short* Bs = smem + 8192;
  const int tid = threadIdx.x;
  const int lane = tid & 63, w = tid >> 6;
  const int cl = lane & 15, gq = lane >> 4;
  const int wm = w >> 1, wn = w & 1;
  const int m0 = blockIdx.y << 7, n0 = blockIdx.x << 7;
  const int mat = n0 >> 11;  // 0=Q 1=K 2=V
  f32x4 acc[4][4];
#pragma unroll
  for (int i = 0; i < 4; ++i)
#pragma unroll
    for (int j = 0; j < 4; ++j) {
      f32x4 z = {0.f, 0.f, 0.f, 0.f};
      acc[i][j] = z;
    }
  const int lrow = lane >> 3;
  const int lseg = (lane & 7) ^ lrow;

  for (int k0 = 0; k0 < DD; k0 += 64) {
#pragma unroll
    for (int i = 0; i < 4; ++i) {
      int r0 = ((w << 2) + i) << 3;
      gll16(&A[(size_t)(m0 + r0 + lrow) * DD + k0 + (lseg << 3)], &As[r0 << 6]);
      gll16(&Bt[(size_t)(n0 + r0 + lrow) * DD + k0 + (lseg << 3)], &Bs[r0 << 6]);
    }
    __syncthreads();
#pragma unroll
    for (int ks = 0; ks < 2; ++ks) {
      bf16x8 af[4], bfr[4];
#pragma unroll
      for (int f = 0; f < 4; ++f) {
        int ra = (wm << 6) + (f << 4) + cl;
        af[f] = *reinterpret_cast<const bf16x8*>(
            &As[((ra << 6) + (ks << 5) + (gq << 3)) ^ ((ra & 7) << 3)]);
        int rb = (wn << 6) + (f << 4) + cl;
        bfr[f] = *reinterpret_cast<const bf16x8*>(
            &Bs[((rb << 6) + (ks << 5) + (gq << 3)) ^ ((rb & 7) << 3)]);
      }
#pragma unroll
      for (int fm = 0; fm < 4; ++fm)
#pragma unroll
        for (int fn = 0; fn < 4; ++fn)
          acc[fm][fn] = __builtin_amdgcn_mfma_f32_16x16x32_bf16(
              af[fm], bfr[fn], acc[fm][fn], 0, 0, 0);
    }
    __syncthreads();
  }

  if (mat < 2) {
    // ---- RoPE epilogue (Q/K). pair partner = lane^1 (col c ^ 1) ----
    const float qs = (mat == 0) ? 0.127517448f : 1.0f;  // (1/sqrt(128))*log2e
    short* Dst = (mat == 0) ? Qb : Kb;
#pragma unroll
    for (int fm = 0; fm < 4; ++fm)
#pragma unroll
      for (int r = 0; r < 4; ++r) {
        int mrow = m0 + (wm << 6) + (fm << 4) + (gq << 2) + r;
        int s = mrow & (SS - 1);
#pragma unroll
        for (int fn = 0; fn < 4; ++fn) {
          int c = (wn << 6) + (fn << 4) + cl;  // head-local col 0..127
          int i = c >> 1;
          float cv = fc[s * 64 + i], sv = fs[s * 64 + i];
          float v = acc[fm][fn][r];
          float vp = __shfl_xor(v, 1, 64);
          float out = (c & 1) ? (v * cv + vp * sv) : (v * cv - vp * sv);
          Dst[(size_t)mrow * DD + ((n0 + c) & (DD - 1))] = f2bf(out * qs);
        }
      }
  } else {
    // ---- V epilogue: transpose via LDS, write Vt (B*H,128,S) ----
    short* Tt = smem;  // [c][r] stride 136 shorts (272B, 16B-aligned rows)
#pragma unroll
    for (int fm = 0; fm < 4; ++fm)
#pragma unroll
      for (int fn = 0; fn < 4; ++fn) {
        int c = (wn << 6) + (fn << 4) + cl;
        int rb = (wm << 6) + (fm << 4) + (gq << 2);
        bf16x4 v4;
#pragma unroll
        for (int rr = 0; rr < 4; ++rr) v4[rr] = f2bf(acc[fm][fn][rr]);
        *reinterpret_cast<bf16x4*>(&Tt[c * 136 + rb]) = v4;
      }
    __syncthreads();
    int d = tid >> 1, half = tid & 1;
    int bq = m0 >> 11, s0loc = m0 & (SS - 1);
    int hv = (n0 >> 7) - 32;  // head 0..15
    size_t vb = (((size_t)(bq * 16 + hv) * HDIM + d) * SS) + s0loc + half * 64;
#pragma unroll
    for (int j = 0; j < 8; ++j) {
      bf16x8 v = *reinterpret_cast<const bf16x8*>(&Tt[d * 136 + half * 64 + j * 8]);
      *reinterpret_cast<bf16x8*>(&Vt[vb + j * 8]) = v;
    }
  }
}

// ---------------- GEMM: C(M,N) = A(M,K) * Bt(N,K)^T, bf16 in, fp32 out (Wo) ----
__global__ __launch_bounds__(256) void gemm_kernel(
    const short* __restrict__ A, const short* __restrict__ Bt, float* __restrict__ C,
    int Mdim, int Ndim, int Kdim) {
  __shared__ short As[128 * 64];
  __shared__ short Bs[128 * 64];
  int tid = threadIdx.x;
  int lane = tid & 63, w = tid >> 6;
  int cl = lane & 15, gq = lane >> 4;
  int wm = w >> 1, wn = w & 1;
  int m0 = blockIdx.y << 7, n0 = blockIdx.x << 7;
  f32x4 acc[4][4];
#pragma unroll
  for (int i = 0; i < 4; ++i)
#pragma unroll
    for (int j = 0; j < 4; ++j) {
      f32x4 z = {0.f, 0.f, 0.f, 0.f};
      acc[i][j] = z;
    }
  int lrow = lane >> 3;
  int lseg = (lane & 7) ^ lrow;

  for (int k0 = 0; k0 < Kdim; k0 += 64) {
#pragma unroll
    for (int i = 0; i < 4; ++i) {
      int r0 = ((w << 2) + i) << 3;
      gll16(&A[(size_t)(m0 + r0 + lrow) * Kdim + k0 + (lseg << 3)], &As[r0 << 6]);
      gll16(&Bt[(size_t)(n0 + r0 + lrow) * Kdim + k0 + (lseg << 3)], &Bs[r0 << 6]);
    }
    __syncthreads();
#pragma unroll
    for (int ks = 0; ks < 2; ++ks) {
      bf16x8 af[4], bfr[4];
#pragma unroll
      for (int f = 0; f < 4; ++f) {
        int ra = (wm << 6) + (f << 4) + cl;
        af[f] = *reinterpret_cast<const bf16x8*>(
            &As[((ra << 6) + (ks << 5) + (gq << 3)) ^ ((ra & 7) << 3)]);
        int rb = (wn << 6) + (f << 4) + cl;
        bfr[f] = *reinterpret_cast<const bf16x8*>(
            &Bs[((rb << 6) + (ks << 5) + (gq << 3)) ^ ((rb & 7) << 3)]);
      }
#pragma unroll
      for (int fm = 0; fm < 4; ++fm)
#pragma unroll
        for (int fn = 0; fn < 4; ++fn)
          acc[fm][fn] = __builtin_amdgcn_mfma_f32_16x16x32_bf16(
              af[fm], bfr[fn], acc[fm][fn], 0, 0, 0);
    }
    __syncthreads();
  }
#pragma unroll
  for (int fm = 0; fm < 4; ++fm)
#pragma unroll
    for (int r = 0; r < 4; ++r) {
      int mrow = m0 + (wm << 6) + (fm << 4) + (gq << 2) + r;
#pragma unroll
      for (int fn = 0; fn < 4; ++fn) {
        int ncol = n0 + (wn << 6) + (fn << 4) + cl;
        C[(size_t)mrow * Ndim + ncol] = acc[fm][fn][r];
      }
    }
}

// ---------------- flash attention, swapped-QK^T 32x32, T3-min pipelined ----------------
// Logits arrive in base-2 units (Q pre-scaled by (1/sqrt(HD))*log2e) -> exp2f.
__global__ __launch_bounds__(256, 2) void attn_kernel(
    const short* __restrict__ Q, const short* __restrict__ K,
    const short* __restrict__ Vt, short* __restrict__ O) {
  __shared__ short Kl[2][64 * 128];
  __shared__ short Vl[2][128 * 64];
  const int id = blockIdx.x;
  const int qi = 15 - (id >> 5);
  const int bh = id & 31;
  const int b = bh >> 4, h = bh & 15;
  const int tid = threadIdx.x;
  const int lane = tid & 63, w = tid >> 6;
  const int l31 = lane & 31, hi = lane >> 5;
  const int qw = qi * 128 + w * 32;
  const int qg = qw + l31;

  const short* Kbase = K + (size_t)b * SS * DD + h * HDIM;
  const short* Vbase = Vt + (size_t)bh * HDIM * SS;
  int krow[4], kq[4], vd[4], vs[4];
#pragma unroll
  for (int i = 0; i < 4; ++i) {
    int c = w * 4 + i;
    krow[i] = c * 4 + (lane >> 4);
    kq[i] = (lane & 15) ^ (krow[i] & 7);
    vd[i] = c * 8 + (lane >> 3);
    vs[i] = (lane & 7) ^ (vd[i] & 7);
  }

  bf16x8 qf[8];
  const size_t qoff = ((size_t)b * SS + qg) * DD + h * HDIM;
#pragma unroll
  for (int s = 0; s < 8; ++s)
    qf[s] = *reinterpret_cast<const bf16x8*>(&Q[qoff + s * 16 + hi * 8]);

  f32x16 ot[4];
#pragma unroll
  for (int dt = 0; dt < 4; ++dt)
#pragma unroll
    for (int r = 0; r < 16; ++r) ot[dt][r] = 0.f;
  float m_run = -INFINITY, l_run = 0.f;

  const int NT = 2 * qi + 2;

#pragma unroll
  for (int i = 0; i < 4; ++i) {
    gll16(Kbase + (size_t)krow[i] * DD + kq[i] * 8, &Kl[0][(w * 4 + i) * 512]);
    gll16(Vbase + (size_t)vd[i] * SS + vs[i] * 8, &Vl[0][(w * 4 + i) * 512]);
  }
  __syncthreads();

  for (int t = 0; t < NT; ++t) {
    const int cur = t & 1;
    if (t + 1 < NT) {
      const int nt64 = (t + 1) * 64;
#pragma unroll
      for (int i = 0; i < 4; ++i) {
        gll16(Kbase + (size_t)(nt64 + krow[i]) * DD + kq[i] * 8,
              &Kl[cur ^ 1][(w * 4 + i) * 512]);
        gll16(Vbase + (size_t)vd[i] * SS + nt64 + vs[i] * 8,
              &Vl[cur ^ 1][(w * 4 + i) * 512]);
      }
    }

    if (t * 64 <= qw + 31) {
      const short* Kc = Kl[cur];
      const short* Vc = Vl[cur];
      f32x16 st0, st1;
#pragma unroll
      for (int r = 0; r < 16; ++r) { st0[r] = 0.f; st1[r] = 0.f; }
      __builtin_amdgcn_s_setprio(1);
#pragma unroll
      for (int s = 0; s < 8; ++s) {
        const int cs = (s * 2 + hi);
        bf16x8 kf0 = *reinterpret_cast<const bf16x8*>(
            &Kc[l31 * 128 + ((cs ^ (l31 & 7)) << 3)]);
        st0 = __builtin_amdgcn_mfma_f32_32x32x16_bf16(kf0, qf[s], st0, 0, 0, 0);
        bf16x8 kf1 = *reinterpret_cast<const bf16x8*>(
            &Kc[(32 + l31) * 128 + ((cs ^ (l31 & 7)) << 3)]);
        st1 = __builtin_amdgcn_mfma_f32_32x32x16_bf16(kf1, qf[s], st1, 0, 0, 0);
      }
      __builtin_amdgcn_s_setprio(0);
      if (t * 64 + 63 > qw) {
#pragma unroll
        for (int r = 0; r < 16; ++r) {
          int dl = (r & 3) + 8 * (r >> 2) + 4 * hi;
          if (t * 64 + dl > qg) st0[r] = -1e30f;
          if (t * 64 + 32 + dl > qg) st1[r] = -1e30f;
        }
      }
      // ---- online softmax (base-2), tree reductions, defer-max ----
      float mx[16];
#pragma unroll
      for (int r = 0; r < 16; ++r) mx[r] = fmaxf(st0[r], st1[r]);
#pragma unroll
      for (int off = 8; off >= 1; off >>= 1)
#pragma unroll
        for (int r = 0; r < 8; ++r)
          if (r < off) mx[r] = fmaxf(mx[r], mx[r + off]);
      float pm = mx[0];
      {
        auto sw = __builtin_amdgcn_permlane32_swap(asi(pm), asi(pm), false, false);
        pm = fmaxf(asf(sw[0]), asf(sw[1]));
      }
      if (!__all(pm <= m_run + 11.5f)) {
        float mn = fmaxf(m_run, pm);
        float al = exp2f(m_run - mn);
        m_run = mn;
        l_run *= al;
#pragma unroll
        for (int dt = 0; dt < 4; ++dt)
#pragma unroll
          for (int r = 0; r < 16; ++r) ot[dt][r] *= al;
      }
#pragma unroll
      for (int r = 0; r < 16; ++r) st0[r] = exp2f(st0[r] - m_run);
#pragma unroll
      for (int r = 0; r < 16; ++r) st1[r] = exp2f(st1[r] - m_run);
      float sm[16];
#pragma unroll
      for (int r = 0; r < 16; ++r) sm[r] = st0[r] + st1[r];
#pragma unroll
      for (int off = 8; off >= 1; off >>= 1)
#pragma unroll
        for (int r = 0; r < 8; ++r)
          if (r < off) sm[r] += sm[r + off];
      float ps = sm[0];
      {
        auto sw = __builtin_amdgcn_permlane32_swap(asi(ps), asi(ps), false, false);
        ps = asf(sw[0]) + asf(sw[1]);
      }
      l_run += ps;

      // ---- pack P -> bf16 B-frags via cvt_pk + permlane32_swap (T12) ----
      bf16x8 pf[4];
#pragma unroll
      for (int s = 0; s < 4; ++s) {
        float e0, e1, e2, e3, e4, e5, e6, e7;
        if (s < 2) {
          e0 = st0[8 * s + 0]; e1 = st0[8 * s + 1]; e2 = st0[8 * s + 2]; e3 = st0[8 * s + 3];
          e4 = st0[8 * s + 4]; e5 = st0[8 * s + 5]; e6 = st0[8 * s + 6]; e7 = st0[8 * s + 7];
        } else {
          e0 = st1[8 * (s - 2) + 0]; e1 = st1[8 * (s - 2) + 1]; e2 = st1[8 * (s - 2) + 2]; e3 = st1[8 * (s - 2) + 3];
          e4 = st1[8 * (s - 2) + 4]; e5 = st1[8 * (s - 2) + 5]; e6 = st1[8 * (s - 2) + 6]; e7 = st1[8 * (s - 2) + 7];
        }
        unsigned a0 = cvtpk_bf16(e0, e1);
        unsigned a1 = cvtpk_bf16(e2, e3);
        unsigned b0 = cvtpk_bf16(e4, e5);
        unsigned b1 = cvtpk_bf16(e6, e7);
        auto r0 = __builtin_amdgcn_permlane32_swap((int)a0, (int)b0, false, false);
        auto r1 = __builtin_amdgcn_permlane32_swap((int)a1, (int)b1, false, false);
        union { int u[4]; bf16x8 v; } pk;
        pk.u[0] = r0[0]; pk.u[1] = r1[0]; pk.u[2] = r0[1]; pk.u[3] = r1[1];
        pf[s] = pk.v;
      }

      __builtin_amdgcn_s_setprio(1);
#pragma unroll
      for (int dt = 0; dt < 4; ++dt) {
        const int vr = dt * 32 + l31;
#pragma unroll
        for (int s = 0; s < 4; ++s) {
          bf16x8 vf = *reinterpret_cast<const bf16x8*>(
              &Vc[vr * 64 + (((s * 2 + hi) ^ (vr & 7)) << 3)]);
          ot[dt] = __builtin_amdgcn_mfma_f32_32x32x16_bf16(vf, pf[s], ot[dt], 0, 0, 0);
        }
      }
      __builtin_amdgcn_s_setprio(0);
    }
    __syncthreads();
  }

  float inv = 1.0f / l_run;
  const size_t orow = ((size_t)b * SS + qg) * DD + h * HDIM;
#pragma unroll
  for (int dt = 0; dt < 4; ++dt)
#pragma unroll
    for (int g = 0; g < 4; ++g) {
      bf16x4 v;
#pragma unroll
      for (int k = 0; k < 4; ++k) v[k] = f2bf(ot[dt][4 * g + k] * inv);
      *reinterpret_cast<bf16x4*>(&O[orow + dt * 32 + 8 * g + 4 * hi]) = v;
    }
}

extern "C" void kernel_launch(void* const* d_in, const int* in_sizes, int n_in,
                              void* d_out, int out_size, void* d_ws, size_t ws_size,
                              hipStream_t stream) {
  const float* x = (const float*)d_in[0];
  const float* Wq = (const float*)d_in[1];
  const float* Wk = (const float*)d_in[2];
  const float* Wv = (const float*)d_in[3];
  const float* Wo = (const float*)d_in[4];
  const float* fc = (const float*)d_in[5];
  const float* fs = (const float*)d_in[6];
  float* out = (float*)d_out;
  char* ws = (char*)d_ws;

  short* xb     = (short*)(ws + 0);                      // 16MB; reused as attn_out
  short* WqkvT  = (short*)(ws + (size_t)16 * 1048576);   // 24MB (6144 x 2048)
  short* WoT    = (short*)(ws + (size_t)40 * 1048576);   // 8MB
  short* Qb     = (short*)(ws + (size_t)48 * 1048576);   // 16MB
  short* Kb     = (short*)(ws + (size_t)64 * 1048576);   // 16MB
  short* VtB    = (short*)(ws + (size_t)80 * 1048576);   // 16MB

  cast_bf16_kernel<<<8192, 256, 0, stream>>>(x, xb, 2097152);
  dim3 tg(32, 32);
  transpose_cast_kernel<<<tg, 256, 0, stream>>>(Wq, WqkvT);
  transpose_cast_kernel<<<tg, 256, 0, stream>>>(Wk, WqkvT + (size_t)2048 * 2048);
  transpose_cast_kernel<<<tg, 256, 0, stream>>>(Wv, WqkvT + (size_t)4096 * 2048);
  transpose_cast_kernel<<<tg, 256, 0, stream>>>(Wo, WoT);

  qkv_gemm_kernel<<<dim3(48, 32), 256, 0, stream>>>(xb, WqkvT, Qb, Kb, VtB, fc, fs);

  attn_kernel<<<512, 256, 0, stream>>>(Qb, Kb, VtB, xb);  // attn_out = xb

  gemm_kernel<<<dim3(16, 32), 256, 0, stream>>>(xb, WoT, out, MM, DD, DD);
}